// Round 3
// baseline (714.373 us; speedup 1.0000x reference)
//
#include <hip/hip_runtime.h>
#include <hip/hip_bf16.h>

typedef __bf16 bf16x8 __attribute__((ext_vector_type(8)));
typedef float  f32x4  __attribute__((ext_vector_type(4)));

#define M_PTS   512
#define D_DIM   10
#define BM      64
#define THREADS 256

// ---------------------------------------------------------------------------
// prep: bt[n][k] = bf16(chol_inv[k][n])   (transposed so B-fragments are
// contiguous in k for dwordx4 loads)
// ---------------------------------------------------------------------------
__global__ void prep_bt(const float* __restrict__ chol,
                        unsigned short* __restrict__ bt) {
    int n = blockIdx.x;
    for (int k = threadIdx.x; k < M_PTS; k += blockDim.x) {
        __hip_bfloat16 h = __float2bfloat16(chol[k * M_PTS + n]);
        bt[n * M_PTS + k] = *reinterpret_cast<unsigned short*>(&h);
    }
}

// ---------------------------------------------------------------------------
// fused: per block of BM=64 rows x full N=512:
//   phase 1: compute k_star[64][512] bf16 into XOR-swizzled LDS
//   phase 2: MFMA 16x16x32 bf16 GEMM vs chol_inv (triangular skip)
// ---------------------------------------------------------------------------
__launch_bounds__(THREADS, 2)
__global__ void fused_kernel(const float* __restrict__ x,
                             const float* __restrict__ pts,
                             const unsigned short* __restrict__ btu,
                             float* __restrict__ out) {
    // k_star tile, bf16 packed 2/word, word-swizzled: word ^= (row&7)<<2
    __shared__ unsigned int ks32[BM * (M_PTS / 2)];   // 64 KB
    __shared__ float        xs[BM * 12];              // 3 KB (rows padded to 12)

    const int tid  = threadIdx.x;
    const size_t row0 = (size_t)blockIdx.x * BM;

    // ---- stage x rows (coalesced) ----
    for (int i = tid; i < BM * D_DIM; i += THREADS) {
        int r = i / D_DIM, j = i - r * D_DIM;
        xs[r * 12 + j] = x[row0 * D_DIM + i];
    }

    // ---- this thread's two pts columns, held in registers ----
    float p0[D_DIM], p1[D_DIM];
    {
        const float* pp = pts + (tid * 2) * D_DIM;
#pragma unroll
        for (int j = 0; j < D_DIM; ++j) { p0[j] = pp[j]; p1[j] = pp[D_DIM + j]; }
    }
    __syncthreads();

    // ---- phase 1: k_star tile (VALU) ----
#pragma unroll 4
    for (int r = 0; r < BM; ++r) {
        const float* xr = &xs[r * 12];
        float d0 = 0.f, d1 = 0.f;
#pragma unroll
        for (int j = 0; j < D_DIM; ++j) {
            float xv = xr[j];
            d0 += fabsf(xv - p0[j]);
            d1 += fabsf(xv - p1[j]);
        }
        float e0 = __expf(-d0);
        float e1 = __expf(-d1);
        __hip_bfloat16 h0 = __float2bfloat16(e0), h1 = __float2bfloat16(e1);
        unsigned pack = (unsigned)(*reinterpret_cast<unsigned short*>(&h0))
                      | ((unsigned)(*reinterpret_cast<unsigned short*>(&h1)) << 16);
        ks32[r * 256 + (tid ^ ((r & 7) << 2))] = pack;
    }
    __syncthreads();

    // ---- phase 2: MFMA ----
    const int lane = tid & 63;
    const int l15  = lane & 15;
    const int hi   = lane >> 4;        // 0..3
    const int w    = tid >> 6;         // wave 0..3

    f32x4 acc[8][4];
#pragma unroll
    for (int f = 0; f < 8; ++f)
#pragma unroll
        for (int m = 0; m < 4; ++m)
            acc[f][m] = (f32x4){0.f, 0.f, 0.f, 0.f};

    for (int step = 0; step < 16; ++step) {
        const int k0 = step * 32;
        // A fragments: ks[row][k0 + hi*8 .. +8], swizzled ds_read_b128
        bf16x8 a[4];
#pragma unroll
        for (int m = 0; m < 4; ++m) {
            int row  = m * 16 + l15;
            int widx = row * 256 + (((k0 >> 1) + hi * 4) ^ ((row & 7) << 2));
            a[m] = *reinterpret_cast<const bf16x8*>(&ks32[widx]);
        }
#pragma unroll
        for (int f = 0; f < 8; ++f) {
            const int nn = (f * 4 + w) * 16;            // interleaved n-frags
            if (nn + 16 <= k0) continue;                // triu: exact skip
            bf16x8 b = *reinterpret_cast<const bf16x8*>(
                btu + (nn + l15) * M_PTS + k0 + hi * 8);
#pragma unroll
            for (int m = 0; m < 4; ++m)
                acc[f][m] = __builtin_amdgcn_mfma_f32_16x16x32_bf16(
                    a[m], b, acc[f][m], 0, 0, 0);
        }
    }

    // ---- epilogue: C/D layout col=lane&15, row=(lane>>4)*4+reg ----
#pragma unroll
    for (int f = 0; f < 8; ++f) {
        int col = (f * 4 + w) * 16 + l15;
#pragma unroll
        for (int m = 0; m < 4; ++m) {
            int rbase = m * 16 + hi * 4;
#pragma unroll
            for (int r = 0; r < 4; ++r)
                out[(row0 + rbase + r) * M_PTS + col] = acc[f][m][r];
        }
    }
}

// ---------------------------------------------------------------------------
extern "C" void kernel_launch(void* const* d_in, const int* in_sizes, int n_in,
                              void* d_out, int out_size, void* d_ws, size_t ws_size,
                              hipStream_t stream) {
    const float* x    = (const float*)d_in[0];
    const float* pts  = (const float*)d_in[1];
    const float* chol = (const float*)d_in[2];
    float* out = (float*)d_out;
    unsigned short* bt = (unsigned short*)d_ws;   // 512*512*2 = 512 KB scratch

    const int nrows = in_sizes[0] / D_DIM;        // 262144

    prep_bt<<<M_PTS, 256, 0, stream>>>(chol, bt);
    fused_kernel<<<nrows / BM, THREADS, 0, stream>>>(x, pts, bt, out);
}